// Round 19
// baseline (116.546 us; speedup 1.0000x reference)
//
#include <hip/hip_runtime.h>
#include <hip/hip_bf16.h>

// Problem constants
#define Bc   128
#define Nc   16
#define Fc   20
#define Dc   4
#define Ec   256
#define Hc   128
#define NBc  10
#define BNc  (Bc*Nc)          // 2048
#define Mrows (BNc*Fc)        // 40960

#define NG   128              // 16-row groups (gi fragment layout / GRU blocks)

typedef __attribute__((ext_vector_type(8))) short short8;
typedef __attribute__((ext_vector_type(4))) float f32x4;
typedef __attribute__((ext_vector_type(2))) unsigned int u32x2;

static __device__ __forceinline__ unsigned short f2bf(float f) {
    union { float f; unsigned u; } v; v.f = f;
    unsigned r = v.u + 0x7fff + ((v.u >> 16) & 1);   // RNE
    return (unsigned short)(r >> 16);
}
static __device__ __forceinline__ float bf2f(unsigned u16) {
    union { unsigned u; float f; } v; v.u = u16 << 16; return v.f;
}
static __device__ __forceinline__ float bfhi2f(unsigned u) {
    union { unsigned uu; float f; } v; v.uu = u & 0xffff0000u; return v.f;
}
static __device__ __forceinline__ float fast_tanh(float v) {
    float t = __expf(2.f * v);
    return 1.f - 2.f * __builtin_amdgcn_rcpf(t + 1.f);
}
static __device__ __forceinline__ float fast_sigmoid(float v) {
    return __builtin_amdgcn_rcpf(1.f + __expf(-v));
}
// tanh(v) = v*(1 + v^2*(-1/3 + v^2*(2/15 - 17/315 v^2))); |v|<~0.45 -> err <1e-5.
static __device__ __forceinline__ float poly_tanh(float v) {
    const float C3 = -0.3333333333f, C5 = 0.1333333333f, C7 = -0.05396825397f;
    float t = v * v;
    float u = fmaf(t, C7, C5);
    u = fmaf(t, u, C3);
    u = fmaf(t, u, 1.0f);
    return v * u;
}

// ---------------------------------------------------------------------------
// K1: feature build v8 — 512 threads/block, halved per-block serial chain.
// Grid (128, 26): y < 20  -> build for (b, f): thread (h = t&127, rq = t>>7)
//                            does 4 rows x 16 j; P3 does 2 rows x 10 gathers.
//                 y >= 20 -> wprep: block covers n = ((y-20)*128+b)*2 + (t>>8).
// ---------------------------------------------------------------------------
__global__ __launch_bounds__(512)
void k_build_x8(const float* __restrict__ ent, const int* __restrict__ bfeat,
                const float* __restrict__ Wp, const float* __restrict__ bp,
                const float* __restrict__ Wr, const float* __restrict__ br,
                const float* __restrict__ emb, unsigned short* __restrict__ x,
                const float* __restrict__ wih, const float* __restrict__ whh,
                unsigned short* __restrict__ wihT, unsigned short* __restrict__ whhT) {
    const int b = blockIdx.x, f = blockIdx.y;
    const int t = threadIdx.x;          // 0..511

    if (f >= Fc) {                      // weight-prep blocks (1536 n total)
        int n = (((f - Fc) * 128 + b) << 1) | (t >> 8);   // 0..1535
        int k = t & 255;
        if (n < 768) wihT[n * 256 + k] = f2bf(wih[k * 768 + n]);
        else         whhT[(n - 768) * 256 + k] = f2bf(whh[k * 768 + (n - 768)]);
        return;
    }

    __shared__ float sC[11 * 128];                          // 5.5 KB
    __shared__ __align__(16) float sDist[16][16];           // 1 KB
    __shared__ int   sIdx[160];
    __shared__ __align__(16) float xtf[16 * 256];           // 16 KB

    for (int s = t; s < 11 * 128; s += 512) {
        int row = s >> 7, hh = s & 127;
        float v;
        if (row < 4)       v = Wp[row * 128 + hh];
        else if (row == 4) v = bp[hh];
        else if (row < 10) v = Wr[(row - 5) * 128 + hh];
        else               v = br[hh];
        sC[s] = v;
    }

    if (t < 256) {                      // P1: pairwise dist (dims 0,1 only)
        int i = t >> 4, j = t & 15;
        float4 ei = *(const float4*)(ent + ((size_t)(b * 16 + i) * 20 + f) * 4);
        float4 ej = *(const float4*)(ent + ((size_t)(b * 16 + j) * 20 + f) * 4);
        float d0 = ei.x - ej.x, d1 = ei.y - ej.y;
        sDist[i][j] = sqrtf(d0 * d0 + d1 * d1);
    } else if (t < 416) {               // bemb indices, parallel with P1
        int tt = t - 256;               // 0..159
        int i = tt / 10, k = tt - i * 10;
        sIdx[tt] = bfeat[((size_t)(b * 16 + i) * 20 + f) * 10 + k];
    }
    __syncthreads();

    const int h  = t & 127;
    const int rq = t >> 7;              // 0..3 -> rows rq*4 .. rq*4+3
    const float w0 = sC[5 * 128 + h], w1 = sC[6 * 128 + h], w2 = sC[7 * 128 + h],
                w3 = sC[8 * 128 + h], w4 = sC[9 * 128 + h], brr = sC[10 * 128 + h];
    const float p0 = sC[0 * 128 + h], p1 = sC[1 * 128 + h], p2 = sC[2 * 128 + h],
                p3 = sC[3 * 128 + h], bpp = sC[4 * 128 + h];
    const float tdiag = poly_tanh(brr);

    float ck[16];
    #pragma unroll
    for (int j = 0; j < 16; ++j) {
        float4 e = *(const float4*)(ent + ((size_t)(b * 16 + j) * 20 + f) * 4);
        float c = e.x * w0;
        c = fmaf(e.y, w1, c); c = fmaf(e.z, w2, c); c = fmaf(e.w, w3, c);
        ck[j] = c;
    }
    #pragma unroll
    for (int ri = 0; ri < 4; ++ri) {
        int i = rq * 4 + ri;
        float4 ev = *(const float4*)(ent + ((size_t)(b * 16 + i) * 20 + f) * 4);
        float pv = bpp;
        pv = fmaf(ev.x, p0, pv); pv = fmaf(ev.y, p1, pv);
        pv = fmaf(ev.z, p2, pv); pv = fmaf(ev.w, p3, pv);
        float base = brr + ck[i];
        float s = 0.f;
        #pragma unroll
        for (int j4 = 0; j4 < 4; ++j4) {            // vectorized: 4 dists/load
            f32x4 d4 = *(const f32x4*)&sDist[i][j4 * 4];
            #pragma unroll
            for (int jj = 0; jj < 4; ++jj) {
                float v = fmaf(w4, d4[jj], base - ck[j4 * 4 + jj]);
                s += poly_tanh(v);
            }
        }
        xtf[i * 256 + h]       = poly_tanh(pv);
        xtf[i * 256 + 128 + h] = s - tdiag;           // diagonal cancelled exactly
    }
    __syncthreads();

    #pragma unroll
    for (int p = 0; p < 2; ++p) {                   // P3: 2 rows/thread
        int i  = p * 8 + (t >> 6);                  // wave-uniform row, 0..15
        int e4 = (t & 63) * 4;
        f32x4 q = *(const f32x4*)&xtf[i * 256 + e4];
        #pragma unroll
        for (int k = 0; k < 10; ++k) {
            int idx = sIdx[i * 10 + k];
            float4 ev = *(const float4*)(emb + (size_t)idx * 256 + e4);
            q[0] += ev.x; q[1] += ev.y; q[2] += ev.z; q[3] += ev.w;
        }
        uint2 o;
        o.x = (unsigned)f2bf(q[0]) | ((unsigned)f2bf(q[1]) << 16);
        o.y = (unsigned)f2bf(q[2]) | ((unsigned)f2bf(q[3]) << 16);
        *(uint2*)(x + ((size_t)f * BNc + b * 16 + i) * 256 + e4) = o;
    }
}

// ---------------------------------------------------------------------------
// K2: gi = x @ w_ih + b_ih — 128-row tiles, 512 thr. (byte-identical R18)
// ---------------------------------------------------------------------------
__global__ __attribute__((amdgpu_flat_work_group_size(512, 512), amdgpu_waves_per_eu(4, 4)))
void k_gi(const unsigned short* __restrict__ x,
          const unsigned short* __restrict__ wihT,
          const float* __restrict__ bih,
          unsigned short* __restrict__ gi) {
    __shared__ __align__(16) unsigned short at[128 * 256];   // 64 KB
    const int mb = blockIdx.x, gb = blockIdx.y;
    const int t = threadIdx.x;            // 0..511
    const int w = t >> 6, l = t & 63, lr = l & 15, lg = l >> 4;
    const int m0 = mb * 128;

    {
        const char* src = (const char*)(x + (size_t)m0 * 256);
        #pragma unroll
        for (int p = 0; p < 8; ++p) {
            int c  = p * 512 + t;
            int rr = c >> 5, cc = c & 31;
            int bo = (rr * 512 + cc * 16) ^ ((rr & 7) << 4);
            *(short8*)((char*)at + bo) = *(const short8*)(src + rr * 512 + cc * 16);
        }
    }
    __syncthreads();

    f32x4 acc[8][2] = {};   // [row-tile][col-tile]
    #pragma unroll
    for (int kk = 0; kk < 8; ++kk) {
        short8 bfr[2];
        #pragma unroll
        for (int ct = 0; ct < 2; ++ct) {
            int col = gb * 256 + (w * 2 + ct) * 16 + lr;
            bfr[ct] = *(const short8*)(wihT + (size_t)col * 256 + kk * 32 + lg * 8);
        }
        #pragma unroll
        for (int rt = 0; rt < 8; ++rt) {
            int row = rt * 16 + lr;
            int bo  = (row * 512 + kk * 64 + lg * 16) ^ ((lr & 7) << 4);
            short8 a = *(const short8*)((const char*)at + bo);
            acc[rt][0] = __builtin_amdgcn_mfma_f32_16x16x32_bf16(a, bfr[0], acc[rt][0], 0, 0, 0);
            acc[rt][1] = __builtin_amdgcn_mfma_f32_16x16x32_bf16(a, bfr[1], acc[rt][1], 0, 0, 0);
        }
    }

    const int f   = m0 / BNc;
    const int bn0 = m0 % BNc;
    #pragma unroll
    for (int ct = 0; ct < 2; ++ct) {
        int wg  = w * 2 + ct;
        int col = gb * 256 + wg * 16 + lr;
        float bv = bih[col];
        #pragma unroll
        for (int rt = 0; rt < 8; ++rt) {
            int g = (bn0 >> 4) + rt;
            u32x2 o;
            o[0] = (unsigned)f2bf(acc[rt][ct][0] + bv) | ((unsigned)f2bf(acc[rt][ct][1] + bv) << 16);
            o[1] = (unsigned)f2bf(acc[rt][ct][2] + bv) | ((unsigned)f2bf(acc[rt][ct][3] + bv) << 16);
            size_t idx = ((((size_t)f * NG + g) * 48) + wg * 3 + gb) * 256 + l * 4;
            __builtin_nontemporal_store(o, (u32x2*)(gi + idx));
        }
    }
}

// ---------------------------------------------------------------------------
// K3: fused GRU — EXACT green-R15/R18 body. Structurally plateaued (~48.5):
// R16 row-split and R17 K-split both regressed; 16x16 MFMA tile is the
// parallelism floor for the 20-step lockstep recurrence.
// ---------------------------------------------------------------------------
#define WL_IDX(w, t, kkr, l) (((((w) * 3 + (t)) * 2 + (kkr)) * 64 + (l)) * 8)

__global__ __attribute__((amdgpu_flat_work_group_size(1024, 1024), amdgpu_waves_per_eu(4, 4)))
void k_gru(const unsigned short* __restrict__ gi,
           const unsigned short* __restrict__ whhT,
           const float* __restrict__ bhh,
           float* __restrict__ out) {
    __shared__ __align__(16) unsigned short hb[2][16 * 256];          // 16 KB, XOR-swizzled
    __shared__ __align__(16) unsigned short wl[16 * 3 * 2 * 64 * 8];  // 96 KB
    int g = blockIdx.x;
    int w = threadIdx.x >> 6, l = threadIdx.x & 63;
    int lr = l & 15, lg = l >> 4;
    int bn0 = g * 16;

    for (int t = threadIdx.x; t < 16 * 256; t += 1024) hb[0][t] = 0;

    short8 wr[3][6];
    #pragma unroll
    for (int t = 0; t < 3; ++t) {
        const unsigned short* wp = whhT + (size_t)(t * 256 + w * 16 + lr) * 256 + lg * 8;
        #pragma unroll
        for (int kk = 0; kk < 6; ++kk) wr[t][kk] = *(const short8*)(wp + kk * 32);
        #pragma unroll
        for (int kk = 6; kk < 8; ++kk)
            *(short8*)&wl[WL_IDX(w, t, kk - 6, l)] = *(const short8*)(wp + kk * 32);
    }
    float bhR = bhh[w * 16 + lr];
    float bhZ = bhh[256 + w * 16 + lr];
    float bhN = bhh[512 + w * 16 + lr];
    __syncthreads();

    float hold[4] = {};
    const unsigned short* gp = gi + ((size_t)g * 48 + w * 3) * 256 + l * 4;
    const size_t fstr = (size_t)NG * 48 * 256;

    uint2 c0 = *(const uint2*)(gp);
    uint2 c1 = *(const uint2*)(gp + 256);
    uint2 c2 = *(const uint2*)(gp + 512);

    for (int f = 0; f < Fc; ++f) {
        const unsigned short* gn = gp + ((f < Fc - 1) ? fstr : 0);
        uint2 n0 = *(const uint2*)(gn);
        uint2 n1 = *(const uint2*)(gn + 256);
        uint2 n2 = *(const uint2*)(gn + 512);
        gp = gn;

        const char* hbuf = (const char*)hb[f & 1];
        f32x4 acc[3] = {};
        #pragma unroll
        for (int kk = 0; kk < 8; ++kk) {
            int bo = (lr * 512 + kk * 64 + lg * 16) ^ ((lr & 7) << 4);
            short8 a = *(const short8*)(hbuf + bo);
            short8 b0, b1, b2;
            if (kk < 6) { b0 = wr[0][kk]; b1 = wr[1][kk]; b2 = wr[2][kk]; }
            else {
                b0 = *(const short8*)&wl[WL_IDX(w, 0, kk - 6, l)];
                b1 = *(const short8*)&wl[WL_IDX(w, 1, kk - 6, l)];
                b2 = *(const short8*)&wl[WL_IDX(w, 2, kk - 6, l)];
            }
            acc[0] = __builtin_amdgcn_mfma_f32_16x16x32_bf16(a, b0, acc[0], 0, 0, 0);
            acc[1] = __builtin_amdgcn_mfma_f32_16x16x32_bf16(a, b1, acc[1], 0, 0, 0);
            acc[2] = __builtin_amdgcn_mfma_f32_16x16x32_bf16(a, b2, acc[2], 0, 0, 0);
        }

        float giR[4] = { bf2f(c0.x & 0xffffu), bfhi2f(c0.x), bf2f(c0.y & 0xffffu), bfhi2f(c0.y) };
        float giZ[4] = { bf2f(c1.x & 0xffffu), bfhi2f(c1.x), bf2f(c1.y & 0xffffu), bfhi2f(c1.y) };
        float giN[4] = { bf2f(c2.x & 0xffffu), bfhi2f(c2.x), bf2f(c2.y & 0xffffu), bfhi2f(c2.y) };

        bool last = (f == Fc - 1);
        char* wbuf = (char*)hb[(f + 1) & 1];
        #pragma unroll
        for (int j = 0; j < 4; ++j) {
            float rg = fast_sigmoid(giR[j] + acc[0][j] + bhR);
            float zg = fast_sigmoid(giZ[j] + acc[1][j] + bhZ);
            float ng = fast_tanh(giN[j] + rg * (acc[2][j] + bhN));
            float h  = (1.f - zg) * ng + zg * hold[j];
            hold[j] = h;
            int row = lg * 4 + j;
            if (last) {
                out[(size_t)(bn0 + row) * Ec + w * 16 + lr] = h;
            } else {
                int bo = (row * 512 + (w * 16 + lr) * 2) ^ ((row & 7) << 4);
                *(unsigned short*)(wbuf + bo) = f2bf(h);
            }
        }
        c0 = n0; c1 = n1; c2 = n2;
        if (!last) __syncthreads();
    }
}

// ---------------------------------------------------------------------------
extern "C" void kernel_launch(void* const* d_in, const int* in_sizes, int n_in,
                              void* d_out, int out_size, void* d_ws, size_t ws_size,
                              hipStream_t stream) {
    const float* ent  = (const float*)d_in[0];
    const int*   bfeat= (const int*)  d_in[1];
    const float* Wp   = (const float*)d_in[2];
    const float* bp   = (const float*)d_in[3];
    const float* Wr   = (const float*)d_in[4];
    const float* br   = (const float*)d_in[5];
    const float* emb  = (const float*)d_in[6];
    const float* wih  = (const float*)d_in[7];
    const float* bih  = (const float*)d_in[8];
    const float* whh  = (const float*)d_in[9];
    const float* bhh  = (const float*)d_in[10];
    float* out = (float*)d_out;

    char* ws = (char*)d_ws;
    unsigned short* x    = (unsigned short*)ws;                           // 21 MB
    unsigned short* gi   = (unsigned short*)(ws + (size_t)Mrows * Ec * 2);// 63 MB
    unsigned short* wihT = (unsigned short*)(ws + (size_t)Mrows * Ec * 2
                                                + (size_t)Mrows * 768 * 2);
    unsigned short* whhT = wihT + (size_t)768 * 256;

    dim3 gx(Bc, Fc + 6);    // y>=Fc blocks do weight prep (2 n per block)
    k_build_x8<<<gx, 512, 0, stream>>>(ent, bfeat, Wp, bp, Wr, br, emb, x,
                                       wih, whh, wihT, whhT);

    dim3 gg(Mrows / 128, 3);
    k_gi<<<gg, 512, 0, stream>>>(x, wihT, bih, gi);

    k_gru<<<NG, 1024, 0, stream>>>(gi, whhT, bhh, out);
}

// Round 20
// 115.650 us; speedup vs baseline: 1.0077x; 1.0077x over previous
//
#include <hip/hip_runtime.h>
#include <hip/hip_bf16.h>

// Problem constants
#define Bc   128
#define Nc   16
#define Fc   20
#define Dc   4
#define Ec   256
#define Hc   128
#define NBc  10
#define BNc  (Bc*Nc)          // 2048
#define Mrows (BNc*Fc)        // 40960

#define NG   128              // 16-row groups (gi fragment layout / GRU blocks)

typedef __attribute__((ext_vector_type(8))) short short8;
typedef __attribute__((ext_vector_type(4))) float f32x4;
typedef __attribute__((ext_vector_type(2))) unsigned int u32x2;

static __device__ __forceinline__ unsigned short f2bf(float f) {
    union { float f; unsigned u; } v; v.f = f;
    unsigned r = v.u + 0x7fff + ((v.u >> 16) & 1);   // RNE
    return (unsigned short)(r >> 16);
}
static __device__ __forceinline__ float bf2f(unsigned u16) {
    union { unsigned u; float f; } v; v.u = u16 << 16; return v.f;
}
static __device__ __forceinline__ float bfhi2f(unsigned u) {
    union { unsigned uu; float f; } v; v.uu = u & 0xffff0000u; return v.f;
}
static __device__ __forceinline__ float fast_tanh(float v) {
    float t = __expf(2.f * v);
    return 1.f - 2.f * __builtin_amdgcn_rcpf(t + 1.f);
}
static __device__ __forceinline__ float fast_sigmoid(float v) {
    return __builtin_amdgcn_rcpf(1.f + __expf(-v));
}
// tanh(v) = v*(1 + v^2*(-1/3 + v^2*(2/15 - 17/315 v^2))); |v|<~0.45 -> err <1e-5.
static __device__ __forceinline__ float poly_tanh(float v) {
    const float C3 = -0.3333333333f, C5 = 0.1333333333f, C7 = -0.05396825397f;
    float t = v * v;
    float u = fmaf(t, C7, C5);
    u = fmaf(t, u, C3);
    u = fmaf(t, u, 1.0f);
    return v * u;
}

// ---------------------------------------------------------------------------
// K0: COALESCED weight transpose+bf16 via LDS 64x64 tiles.
// w[256][768] -> wT[768][256]. Read: 64 contiguous n/lane-group (256 B).
// Write: 64 contiguous k shorts (128 B). tile[64][65] -> conflict-free.
// 96 blocks (48 per matrix), 256 thr. Replaces the uncoalesced strided
// per-lane transpose that was serializing as a tail inside the build grid.
// ---------------------------------------------------------------------------
__global__ __launch_bounds__(256)
void k_wprepT(const float* __restrict__ wih, const float* __restrict__ whh,
              unsigned short* __restrict__ wihT, unsigned short* __restrict__ whhT) {
    __shared__ float tile[64][65];
    const int blk = blockIdx.x;            // 0..95
    const float* src = (blk < 48) ? wih : whh;
    unsigned short* dst = (blk < 48) ? wihT : whhT;
    const int b2 = blk % 48;
    const int k0 = (b2 & 3) * 64;          // 256 = 4 k-tiles
    const int n0 = (b2 >> 2) * 64;         // 768 = 12 n-tiles
    const int t = threadIdx.x;
    const int lane = t & 63, grp = t >> 6;

    #pragma unroll
    for (int r = 0; r < 16; ++r) {
        int kl = grp + r * 4;
        tile[kl][lane] = src[(size_t)(k0 + kl) * 768 + n0 + lane];
    }
    __syncthreads();
    #pragma unroll
    for (int r = 0; r < 16; ++r) {
        int nl = grp + r * 4;
        dst[(size_t)(n0 + nl) * 256 + k0 + lane] = f2bf(tile[lane][nl]);
    }
}

// ---------------------------------------------------------------------------
// K1: feature build v7 — poly tanh, 256 thr, grid (128 b, 20 f).
// (R18 body with the inline-wprep branch removed.)
// ---------------------------------------------------------------------------
__global__ __launch_bounds__(256)
void k_build_x7(const float* __restrict__ ent, const int* __restrict__ bfeat,
                const float* __restrict__ Wp, const float* __restrict__ bp,
                const float* __restrict__ Wr, const float* __restrict__ br,
                const float* __restrict__ emb, unsigned short* __restrict__ x) {
    __shared__ float sC[11 * 128];                          // 5.5 KB
    __shared__ __align__(16) float sDist[16][16];           // 1 KB
    __shared__ int   sIdx[160];
    __shared__ __align__(16) float xtf[16 * 256];           // 16 KB

    const int b = blockIdx.x, f = blockIdx.y;
    const int t = threadIdx.x;

    for (int s = t; s < 11 * 128; s += 256) {
        int row = s >> 7, hh = s & 127;
        float v;
        if (row < 4)       v = Wp[row * 128 + hh];
        else if (row == 4) v = bp[hh];
        else if (row < 10) v = Wr[(row - 5) * 128 + hh];
        else               v = br[hh];
        sC[s] = v;
    }

    {
        int i = t >> 4, j = t & 15;
        float4 ei = *(const float4*)(ent + ((size_t)(b * 16 + i) * 20 + f) * 4);
        float4 ej = *(const float4*)(ent + ((size_t)(b * 16 + j) * 20 + f) * 4);
        float d0 = ei.x - ej.x, d1 = ei.y - ej.y;
        sDist[i][j] = sqrtf(d0 * d0 + d1 * d1);      // dims 0,1 only (reference)
    }
    if (t < 160) {
        int i = t / 10, k = t - i * 10;
        sIdx[t] = bfeat[((size_t)(b * 16 + i) * 20 + f) * 10 + k];
    }
    __syncthreads();

    const int h  = t & 127;
    const int rh = t >> 7;
    const float w0 = sC[5 * 128 + h], w1 = sC[6 * 128 + h], w2 = sC[7 * 128 + h],
                w3 = sC[8 * 128 + h], w4 = sC[9 * 128 + h], brr = sC[10 * 128 + h];
    const float p0 = sC[0 * 128 + h], p1 = sC[1 * 128 + h], p2 = sC[2 * 128 + h],
                p3 = sC[3 * 128 + h], bpp = sC[4 * 128 + h];
    const float tdiag = poly_tanh(brr);

    float ck[16];
    #pragma unroll
    for (int j = 0; j < 16; ++j) {
        float4 e = *(const float4*)(ent + ((size_t)(b * 16 + j) * 20 + f) * 4);
        float c = e.x * w0;
        c = fmaf(e.y, w1, c); c = fmaf(e.z, w2, c); c = fmaf(e.w, w3, c);
        ck[j] = c;
    }
    #pragma unroll
    for (int ri = 0; ri < 8; ++ri) {
        int i = rh * 8 + ri;
        float4 ev = *(const float4*)(ent + ((size_t)(b * 16 + i) * 20 + f) * 4);
        float pv = bpp;
        pv = fmaf(ev.x, p0, pv); pv = fmaf(ev.y, p1, pv);
        pv = fmaf(ev.z, p2, pv); pv = fmaf(ev.w, p3, pv);
        float base = brr + ck[i];
        float s = 0.f;
        #pragma unroll
        for (int j4 = 0; j4 < 4; ++j4) {            // vectorized: 4 dists/load
            f32x4 d4 = *(const f32x4*)&sDist[i][j4 * 4];
            #pragma unroll
            for (int jj = 0; jj < 4; ++jj) {
                float v = fmaf(w4, d4[jj], base - ck[j4 * 4 + jj]);
                s += poly_tanh(v);
            }
        }
        xtf[i * 256 + h]       = poly_tanh(pv);
        xtf[i * 256 + 128 + h] = s - tdiag;           // diagonal cancelled exactly
    }
    __syncthreads();

    #pragma unroll
    for (int p = 0; p < 4; ++p) {
        int i  = p * 4 + (t >> 6);                // wave-uniform row
        int e4 = (t & 63) * 4;
        f32x4 q = *(const f32x4*)&xtf[i * 256 + e4];
        #pragma unroll
        for (int k = 0; k < 10; ++k) {
            int idx = sIdx[i * 10 + k];
            float4 ev = *(const float4*)(emb + (size_t)idx * 256 + e4);
            q[0] += ev.x; q[1] += ev.y; q[2] += ev.z; q[3] += ev.w;
        }
        uint2 o;
        o.x = (unsigned)f2bf(q[0]) | ((unsigned)f2bf(q[1]) << 16);
        o.y = (unsigned)f2bf(q[2]) | ((unsigned)f2bf(q[3]) << 16);
        *(uint2*)(x + ((size_t)f * BNc + b * 16 + i) * 256 + e4) = o;
    }
}

// ---------------------------------------------------------------------------
// K2: gi = x @ w_ih + b_ih — 128-row tiles, 512 thr. (byte-identical R18)
// ---------------------------------------------------------------------------
__global__ __attribute__((amdgpu_flat_work_group_size(512, 512), amdgpu_waves_per_eu(4, 4)))
void k_gi(const unsigned short* __restrict__ x,
          const unsigned short* __restrict__ wihT,
          const float* __restrict__ bih,
          unsigned short* __restrict__ gi) {
    __shared__ __align__(16) unsigned short at[128 * 256];   // 64 KB
    const int mb = blockIdx.x, gb = blockIdx.y;
    const int t = threadIdx.x;            // 0..511
    const int w = t >> 6, l = t & 63, lr = l & 15, lg = l >> 4;
    const int m0 = mb * 128;

    {
        const char* src = (const char*)(x + (size_t)m0 * 256);
        #pragma unroll
        for (int p = 0; p < 8; ++p) {
            int c  = p * 512 + t;
            int rr = c >> 5, cc = c & 31;
            int bo = (rr * 512 + cc * 16) ^ ((rr & 7) << 4);
            *(short8*)((char*)at + bo) = *(const short8*)(src + rr * 512 + cc * 16);
        }
    }
    __syncthreads();

    f32x4 acc[8][2] = {};   // [row-tile][col-tile]
    #pragma unroll
    for (int kk = 0; kk < 8; ++kk) {
        short8 bfr[2];
        #pragma unroll
        for (int ct = 0; ct < 2; ++ct) {
            int col = gb * 256 + (w * 2 + ct) * 16 + lr;
            bfr[ct] = *(const short8*)(wihT + (size_t)col * 256 + kk * 32 + lg * 8);
        }
        #pragma unroll
        for (int rt = 0; rt < 8; ++rt) {
            int row = rt * 16 + lr;
            int bo  = (row * 512 + kk * 64 + lg * 16) ^ ((lr & 7) << 4);
            short8 a = *(const short8*)((const char*)at + bo);
            acc[rt][0] = __builtin_amdgcn_mfma_f32_16x16x32_bf16(a, bfr[0], acc[rt][0], 0, 0, 0);
            acc[rt][1] = __builtin_amdgcn_mfma_f32_16x16x32_bf16(a, bfr[1], acc[rt][1], 0, 0, 0);
        }
    }

    const int f   = m0 / BNc;
    const int bn0 = m0 % BNc;
    #pragma unroll
    for (int ct = 0; ct < 2; ++ct) {
        int wg  = w * 2 + ct;
        int col = gb * 256 + wg * 16 + lr;
        float bv = bih[col];
        #pragma unroll
        for (int rt = 0; rt < 8; ++rt) {
            int g = (bn0 >> 4) + rt;
            u32x2 o;
            o[0] = (unsigned)f2bf(acc[rt][ct][0] + bv) | ((unsigned)f2bf(acc[rt][ct][1] + bv) << 16);
            o[1] = (unsigned)f2bf(acc[rt][ct][2] + bv) | ((unsigned)f2bf(acc[rt][ct][3] + bv) << 16);
            size_t idx = ((((size_t)f * NG + g) * 48) + wg * 3 + gb) * 256 + l * 4;
            __builtin_nontemporal_store(o, (u32x2*)(gi + idx));
        }
    }
}

// ---------------------------------------------------------------------------
// K3: fused GRU — EXACT green-R15/R18 body (structurally plateaued ~48.5 µs).
// ---------------------------------------------------------------------------
#define WL_IDX(w, t, kkr, l) (((((w) * 3 + (t)) * 2 + (kkr)) * 64 + (l)) * 8)

__global__ __attribute__((amdgpu_flat_work_group_size(1024, 1024), amdgpu_waves_per_eu(4, 4)))
void k_gru(const unsigned short* __restrict__ gi,
           const unsigned short* __restrict__ whhT,
           const float* __restrict__ bhh,
           float* __restrict__ out) {
    __shared__ __align__(16) unsigned short hb[2][16 * 256];          // 16 KB, XOR-swizzled
    __shared__ __align__(16) unsigned short wl[16 * 3 * 2 * 64 * 8];  // 96 KB
    int g = blockIdx.x;
    int w = threadIdx.x >> 6, l = threadIdx.x & 63;
    int lr = l & 15, lg = l >> 4;
    int bn0 = g * 16;

    for (int t = threadIdx.x; t < 16 * 256; t += 1024) hb[0][t] = 0;

    short8 wr[3][6];
    #pragma unroll
    for (int t = 0; t < 3; ++t) {
        const unsigned short* wp = whhT + (size_t)(t * 256 + w * 16 + lr) * 256 + lg * 8;
        #pragma unroll
        for (int kk = 0; kk < 6; ++kk) wr[t][kk] = *(const short8*)(wp + kk * 32);
        #pragma unroll
        for (int kk = 6; kk < 8; ++kk)
            *(short8*)&wl[WL_IDX(w, t, kk - 6, l)] = *(const short8*)(wp + kk * 32);
    }
    float bhR = bhh[w * 16 + lr];
    float bhZ = bhh[256 + w * 16 + lr];
    float bhN = bhh[512 + w * 16 + lr];
    __syncthreads();

    float hold[4] = {};
    const unsigned short* gp = gi + ((size_t)g * 48 + w * 3) * 256 + l * 4;
    const size_t fstr = (size_t)NG * 48 * 256;

    uint2 c0 = *(const uint2*)(gp);
    uint2 c1 = *(const uint2*)(gp + 256);
    uint2 c2 = *(const uint2*)(gp + 512);

    for (int f = 0; f < Fc; ++f) {
        const unsigned short* gn = gp + ((f < Fc - 1) ? fstr : 0);
        uint2 n0 = *(const uint2*)(gn);
        uint2 n1 = *(const uint2*)(gn + 256);
        uint2 n2 = *(const uint2*)(gn + 512);
        gp = gn;

        const char* hbuf = (const char*)hb[f & 1];
        f32x4 acc[3] = {};
        #pragma unroll
        for (int kk = 0; kk < 8; ++kk) {
            int bo = (lr * 512 + kk * 64 + lg * 16) ^ ((lr & 7) << 4);
            short8 a = *(const short8*)(hbuf + bo);
            short8 b0, b1, b2;
            if (kk < 6) { b0 = wr[0][kk]; b1 = wr[1][kk]; b2 = wr[2][kk]; }
            else {
                b0 = *(const short8*)&wl[WL_IDX(w, 0, kk - 6, l)];
                b1 = *(const short8*)&wl[WL_IDX(w, 1, kk - 6, l)];
                b2 = *(const short8*)&wl[WL_IDX(w, 2, kk - 6, l)];
            }
            acc[0] = __builtin_amdgcn_mfma_f32_16x16x32_bf16(a, b0, acc[0], 0, 0, 0);
            acc[1] = __builtin_amdgcn_mfma_f32_16x16x32_bf16(a, b1, acc[1], 0, 0, 0);
            acc[2] = __builtin_amdgcn_mfma_f32_16x16x32_bf16(a, b2, acc[2], 0, 0, 0);
        }

        float giR[4] = { bf2f(c0.x & 0xffffu), bfhi2f(c0.x), bf2f(c0.y & 0xffffu), bfhi2f(c0.y) };
        float giZ[4] = { bf2f(c1.x & 0xffffu), bfhi2f(c1.x), bf2f(c1.y & 0xffffu), bfhi2f(c1.y) };
        float giN[4] = { bf2f(c2.x & 0xffffu), bfhi2f(c2.x), bf2f(c2.y & 0xffffu), bfhi2f(c2.y) };

        bool last = (f == Fc - 1);
        char* wbuf = (char*)hb[(f + 1) & 1];
        #pragma unroll
        for (int j = 0; j < 4; ++j) {
            float rg = fast_sigmoid(giR[j] + acc[0][j] + bhR);
            float zg = fast_sigmoid(giZ[j] + acc[1][j] + bhZ);
            float ng = fast_tanh(giN[j] + rg * (acc[2][j] + bhN));
            float h  = (1.f - zg) * ng + zg * hold[j];
            hold[j] = h;
            int row = lg * 4 + j;
            if (last) {
                out[(size_t)(bn0 + row) * Ec + w * 16 + lr] = h;
            } else {
                int bo = (row * 512 + (w * 16 + lr) * 2) ^ ((row & 7) << 4);
                *(unsigned short*)(wbuf + bo) = f2bf(h);
            }
        }
        c0 = n0; c1 = n1; c2 = n2;
        if (!last) __syncthreads();
    }
}

// ---------------------------------------------------------------------------
extern "C" void kernel_launch(void* const* d_in, const int* in_sizes, int n_in,
                              void* d_out, int out_size, void* d_ws, size_t ws_size,
                              hipStream_t stream) {
    const float* ent  = (const float*)d_in[0];
    const int*   bfeat= (const int*)  d_in[1];
    const float* Wp   = (const float*)d_in[2];
    const float* bp   = (const float*)d_in[3];
    const float* Wr   = (const float*)d_in[4];
    const float* br   = (const float*)d_in[5];
    const float* emb  = (const float*)d_in[6];
    const float* wih  = (const float*)d_in[7];
    const float* bih  = (const float*)d_in[8];
    const float* whh  = (const float*)d_in[9];
    const float* bhh  = (const float*)d_in[10];
    float* out = (float*)d_out;

    char* ws = (char*)d_ws;
    unsigned short* x    = (unsigned short*)ws;                           // 21 MB
    unsigned short* gi   = (unsigned short*)(ws + (size_t)Mrows * Ec * 2);// 63 MB
    unsigned short* wihT = (unsigned short*)(ws + (size_t)Mrows * Ec * 2
                                                + (size_t)Mrows * 768 * 2);
    unsigned short* whhT = wihT + (size_t)768 * 256;

    k_wprepT<<<96, 256, 0, stream>>>(wih, whh, wihT, whhT);

    dim3 gx(Bc, Fc);
    k_build_x7<<<gx, 256, 0, stream>>>(ent, bfeat, Wp, bp, Wr, br, emb, x);

    dim3 gg(Mrows / 128, 3);
    k_gi<<<gg, 512, 0, stream>>>(x, wihT, bih, gi);

    k_gru<<<NG, 1024, 0, stream>>>(gi, whhT, bhh, out);
}

// Round 21
// 110.802 us; speedup vs baseline: 1.0518x; 1.0438x over previous
//
#include <hip/hip_runtime.h>
#include <hip/hip_bf16.h>

// Problem constants
#define Bc   128
#define Nc   16
#define Fc   20
#define Dc   4
#define Ec   256
#define Hc   128
#define NBc  10
#define BNc  (Bc*Nc)          // 2048
#define Mrows (BNc*Fc)        // 40960

#define NG   128              // 16-row groups (gi fragment layout / GRU blocks)

typedef __attribute__((ext_vector_type(8))) short short8;
typedef __attribute__((ext_vector_type(4))) float f32x4;
typedef __attribute__((ext_vector_type(2))) unsigned int u32x2;

static __device__ __forceinline__ unsigned short f2bf(float f) {
    union { float f; unsigned u; } v; v.f = f;
    unsigned r = v.u + 0x7fff + ((v.u >> 16) & 1);   // RNE
    return (unsigned short)(r >> 16);
}
static __device__ __forceinline__ float bf2f(unsigned u16) {
    union { unsigned u; float f; } v; v.u = u16 << 16; return v.f;
}
static __device__ __forceinline__ float bfhi2f(unsigned u) {
    union { unsigned uu; float f; } v; v.uu = u & 0xffff0000u; return v.f;
}
static __device__ __forceinline__ float fast_tanh(float v) {
    float t = __expf(2.f * v);
    return 1.f - 2.f * __builtin_amdgcn_rcpf(t + 1.f);
}
static __device__ __forceinline__ float fast_sigmoid(float v) {
    return __builtin_amdgcn_rcpf(1.f + __expf(-v));
}
// tanh(v) = v*(1 + v^2*(-1/3 + v^2*(2/15 - 17/315 v^2))); |v|<~0.45 -> err <1e-5.
static __device__ __forceinline__ float poly_tanh(float v) {
    const float C3 = -0.3333333333f, C5 = 0.1333333333f, C7 = -0.05396825397f;
    float t = v * v;
    float u = fmaf(t, C7, C5);
    u = fmaf(t, u, C3);
    u = fmaf(t, u, 1.0f);
    return v * u;
}

// ---------------------------------------------------------------------------
// K1: feature build v7 + INLINE weight prep.  (exact R18-green configuration)
// Grid (128, 32): blockIdx.y < 20  -> build work for (b, f)
//                 blockIdx.y >= 20 -> wprep: n = (y-20)*128 + x (1536 vals)
// The wprep blocks touch no LDS and exit before any barrier (whole-block
// uniform branch -> safe). wihT/whhT are consumed only by LATER launches.
// ---------------------------------------------------------------------------
__global__ __launch_bounds__(256)
void k_build_x7(const float* __restrict__ ent, const int* __restrict__ bfeat,
                const float* __restrict__ Wp, const float* __restrict__ bp,
                const float* __restrict__ Wr, const float* __restrict__ br,
                const float* __restrict__ emb, unsigned short* __restrict__ x,
                const float* __restrict__ wih, const float* __restrict__ whh,
                unsigned short* __restrict__ wihT, unsigned short* __restrict__ whhT) {
    const int b = blockIdx.x, f = blockIdx.y;
    const int t = threadIdx.x;

    if (f >= Fc) {                      // weight-prep blocks
        int n = (f - Fc) * 128 + b;     // 0..1535
        if (n < 768) wihT[n * 256 + t] = f2bf(wih[t * 768 + n]);
        else         whhT[(n - 768) * 256 + t] = f2bf(whh[t * 768 + (n - 768)]);
        return;
    }

    __shared__ float sC[11 * 128];                          // 5.5 KB
    __shared__ __align__(16) float sDist[16][16];           // 1 KB
    __shared__ int   sIdx[160];
    __shared__ __align__(16) float xtf[16 * 256];           // 16 KB

    for (int s = t; s < 11 * 128; s += 256) {
        int row = s >> 7, hh = s & 127;
        float v;
        if (row < 4)       v = Wp[row * 128 + hh];
        else if (row == 4) v = bp[hh];
        else if (row < 10) v = Wr[(row - 5) * 128 + hh];
        else               v = br[hh];
        sC[s] = v;
    }

    {
        int i = t >> 4, j = t & 15;
        float4 ei = *(const float4*)(ent + ((size_t)(b * 16 + i) * 20 + f) * 4);
        float4 ej = *(const float4*)(ent + ((size_t)(b * 16 + j) * 20 + f) * 4);
        float d0 = ei.x - ej.x, d1 = ei.y - ej.y;
        sDist[i][j] = sqrtf(d0 * d0 + d1 * d1);      // dims 0,1 only (reference)
    }
    if (t < 160) {
        int i = t / 10, k = t - i * 10;
        sIdx[t] = bfeat[((size_t)(b * 16 + i) * 20 + f) * 10 + k];
    }
    __syncthreads();

    const int h  = t & 127;
    const int rh = t >> 7;
    const float w0 = sC[5 * 128 + h], w1 = sC[6 * 128 + h], w2 = sC[7 * 128 + h],
                w3 = sC[8 * 128 + h], w4 = sC[9 * 128 + h], brr = sC[10 * 128 + h];
    const float p0 = sC[0 * 128 + h], p1 = sC[1 * 128 + h], p2 = sC[2 * 128 + h],
                p3 = sC[3 * 128 + h], bpp = sC[4 * 128 + h];
    const float tdiag = poly_tanh(brr);

    float ck[16];
    #pragma unroll
    for (int j = 0; j < 16; ++j) {
        float4 e = *(const float4*)(ent + ((size_t)(b * 16 + j) * 20 + f) * 4);
        float c = e.x * w0;
        c = fmaf(e.y, w1, c); c = fmaf(e.z, w2, c); c = fmaf(e.w, w3, c);
        ck[j] = c;
    }
    #pragma unroll
    for (int ri = 0; ri < 8; ++ri) {
        int i = rh * 8 + ri;
        float4 ev = *(const float4*)(ent + ((size_t)(b * 16 + i) * 20 + f) * 4);
        float pv = bpp;
        pv = fmaf(ev.x, p0, pv); pv = fmaf(ev.y, p1, pv);
        pv = fmaf(ev.z, p2, pv); pv = fmaf(ev.w, p3, pv);
        float base = brr + ck[i];
        float s = 0.f;
        #pragma unroll
        for (int j4 = 0; j4 < 4; ++j4) {            // vectorized: 4 dists/load
            f32x4 d4 = *(const f32x4*)&sDist[i][j4 * 4];
            #pragma unroll
            for (int jj = 0; jj < 4; ++jj) {
                float v = fmaf(w4, d4[jj], base - ck[j4 * 4 + jj]);
                s += poly_tanh(v);
            }
        }
        xtf[i * 256 + h]       = poly_tanh(pv);
        xtf[i * 256 + 128 + h] = s - tdiag;           // diagonal cancelled exactly
    }
    __syncthreads();

    #pragma unroll
    for (int p = 0; p < 4; ++p) {
        int i  = p * 4 + (t >> 6);                // wave-uniform row
        int e4 = (t & 63) * 4;
        f32x4 q = *(const f32x4*)&xtf[i * 256 + e4];
        #pragma unroll
        for (int k = 0; k < 10; ++k) {
            int idx = sIdx[i * 10 + k];
            float4 ev = *(const float4*)(emb + (size_t)idx * 256 + e4);
            q[0] += ev.x; q[1] += ev.y; q[2] += ev.z; q[3] += ev.w;
        }
        uint2 o;
        o.x = (unsigned)f2bf(q[0]) | ((unsigned)f2bf(q[1]) << 16);
        o.y = (unsigned)f2bf(q[2]) | ((unsigned)f2bf(q[3]) << 16);
        *(uint2*)(x + ((size_t)f * BNc + b * 16 + i) * 256 + e4) = o;
    }
}

// ---------------------------------------------------------------------------
// K2: gi = x @ w_ih + b_ih — 128-row tiles, 512 thr. (byte-identical R18)
// ---------------------------------------------------------------------------
__global__ __attribute__((amdgpu_flat_work_group_size(512, 512), amdgpu_waves_per_eu(4, 4)))
void k_gi(const unsigned short* __restrict__ x,
          const unsigned short* __restrict__ wihT,
          const float* __restrict__ bih,
          unsigned short* __restrict__ gi) {
    __shared__ __align__(16) unsigned short at[128 * 256];   // 64 KB
    const int mb = blockIdx.x, gb = blockIdx.y;
    const int t = threadIdx.x;            // 0..511
    const int w = t >> 6, l = t & 63, lr = l & 15, lg = l >> 4;
    const int m0 = mb * 128;

    {
        const char* src = (const char*)(x + (size_t)m0 * 256);
        #pragma unroll
        for (int p = 0; p < 8; ++p) {
            int c  = p * 512 + t;
            int rr = c >> 5, cc = c & 31;
            int bo = (rr * 512 + cc * 16) ^ ((rr & 7) << 4);
            *(short8*)((char*)at + bo) = *(const short8*)(src + rr * 512 + cc * 16);
        }
    }
    __syncthreads();

    f32x4 acc[8][2] = {};   // [row-tile][col-tile]
    #pragma unroll
    for (int kk = 0; kk < 8; ++kk) {
        short8 bfr[2];
        #pragma unroll
        for (int ct = 0; ct < 2; ++ct) {
            int col = gb * 256 + (w * 2 + ct) * 16 + lr;
            bfr[ct] = *(const short8*)(wihT + (size_t)col * 256 + kk * 32 + lg * 8);
        }
        #pragma unroll
        for (int rt = 0; rt < 8; ++rt) {
            int row = rt * 16 + lr;
            int bo  = (row * 512 + kk * 64 + lg * 16) ^ ((lr & 7) << 4);
            short8 a = *(const short8*)((const char*)at + bo);
            acc[rt][0] = __builtin_amdgcn_mfma_f32_16x16x32_bf16(a, bfr[0], acc[rt][0], 0, 0, 0);
            acc[rt][1] = __builtin_amdgcn_mfma_f32_16x16x32_bf16(a, bfr[1], acc[rt][1], 0, 0, 0);
        }
    }

    const int f   = m0 / BNc;
    const int bn0 = m0 % BNc;
    #pragma unroll
    for (int ct = 0; ct < 2; ++ct) {
        int wg  = w * 2 + ct;
        int col = gb * 256 + wg * 16 + lr;
        float bv = bih[col];
        #pragma unroll
        for (int rt = 0; rt < 8; ++rt) {
            int g = (bn0 >> 4) + rt;
            u32x2 o;
            o[0] = (unsigned)f2bf(acc[rt][ct][0] + bv) | ((unsigned)f2bf(acc[rt][ct][1] + bv) << 16);
            o[1] = (unsigned)f2bf(acc[rt][ct][2] + bv) | ((unsigned)f2bf(acc[rt][ct][3] + bv) << 16);
            size_t idx = ((((size_t)f * NG + g) * 48) + wg * 3 + gb) * 256 + l * 4;
            __builtin_nontemporal_store(o, (u32x2*)(gi + idx));
        }
    }
}

// ---------------------------------------------------------------------------
// K3: fused GRU — EXACT green-R15/R18 body (structurally plateaued ~48.5 µs:
// R16 row-split and R17 K-split both regressed; 16x16 MFMA tile is the
// parallelism floor for the 20-step lockstep recurrence).
// ---------------------------------------------------------------------------
#define WL_IDX(w, t, kkr, l) (((((w) * 3 + (t)) * 2 + (kkr)) * 64 + (l)) * 8)

__global__ __attribute__((amdgpu_flat_work_group_size(1024, 1024), amdgpu_waves_per_eu(4, 4)))
void k_gru(const unsigned short* __restrict__ gi,
           const unsigned short* __restrict__ whhT,
           const float* __restrict__ bhh,
           float* __restrict__ out) {
    __shared__ __align__(16) unsigned short hb[2][16 * 256];          // 16 KB, XOR-swizzled
    __shared__ __align__(16) unsigned short wl[16 * 3 * 2 * 64 * 8];  // 96 KB
    int g = blockIdx.x;
    int w = threadIdx.x >> 6, l = threadIdx.x & 63;
    int lr = l & 15, lg = l >> 4;
    int bn0 = g * 16;

    for (int t = threadIdx.x; t < 16 * 256; t += 1024) hb[0][t] = 0;

    short8 wr[3][6];
    #pragma unroll
    for (int t = 0; t < 3; ++t) {
        const unsigned short* wp = whhT + (size_t)(t * 256 + w * 16 + lr) * 256 + lg * 8;
        #pragma unroll
        for (int kk = 0; kk < 6; ++kk) wr[t][kk] = *(const short8*)(wp + kk * 32);
        #pragma unroll
        for (int kk = 6; kk < 8; ++kk)
            *(short8*)&wl[WL_IDX(w, t, kk - 6, l)] = *(const short8*)(wp + kk * 32);
    }
    float bhR = bhh[w * 16 + lr];
    float bhZ = bhh[256 + w * 16 + lr];
    float bhN = bhh[512 + w * 16 + lr];
    __syncthreads();

    float hold[4] = {};
    const unsigned short* gp = gi + ((size_t)g * 48 + w * 3) * 256 + l * 4;
    const size_t fstr = (size_t)NG * 48 * 256;

    uint2 c0 = *(const uint2*)(gp);
    uint2 c1 = *(const uint2*)(gp + 256);
    uint2 c2 = *(const uint2*)(gp + 512);

    for (int f = 0; f < Fc; ++f) {
        const unsigned short* gn = gp + ((f < Fc - 1) ? fstr : 0);
        uint2 n0 = *(const uint2*)(gn);
        uint2 n1 = *(const uint2*)(gn + 256);
        uint2 n2 = *(const uint2*)(gn + 512);
        gp = gn;

        const char* hbuf = (const char*)hb[f & 1];
        f32x4 acc[3] = {};
        #pragma unroll
        for (int kk = 0; kk < 8; ++kk) {
            int bo = (lr * 512 + kk * 64 + lg * 16) ^ ((lr & 7) << 4);
            short8 a = *(const short8*)(hbuf + bo);
            short8 b0, b1, b2;
            if (kk < 6) { b0 = wr[0][kk]; b1 = wr[1][kk]; b2 = wr[2][kk]; }
            else {
                b0 = *(const short8*)&wl[WL_IDX(w, 0, kk - 6, l)];
                b1 = *(const short8*)&wl[WL_IDX(w, 1, kk - 6, l)];
                b2 = *(const short8*)&wl[WL_IDX(w, 2, kk - 6, l)];
            }
            acc[0] = __builtin_amdgcn_mfma_f32_16x16x32_bf16(a, b0, acc[0], 0, 0, 0);
            acc[1] = __builtin_amdgcn_mfma_f32_16x16x32_bf16(a, b1, acc[1], 0, 0, 0);
            acc[2] = __builtin_amdgcn_mfma_f32_16x16x32_bf16(a, b2, acc[2], 0, 0, 0);
        }

        float giR[4] = { bf2f(c0.x & 0xffffu), bfhi2f(c0.x), bf2f(c0.y & 0xffffu), bfhi2f(c0.y) };
        float giZ[4] = { bf2f(c1.x & 0xffffu), bfhi2f(c1.x), bf2f(c1.y & 0xffffu), bfhi2f(c1.y) };
        float giN[4] = { bf2f(c2.x & 0xffffu), bfhi2f(c2.x), bf2f(c2.y & 0xffffu), bfhi2f(c2.y) };

        bool last = (f == Fc - 1);
        char* wbuf = (char*)hb[(f + 1) & 1];
        #pragma unroll
        for (int j = 0; j < 4; ++j) {
            float rg = fast_sigmoid(giR[j] + acc[0][j] + bhR);
            float zg = fast_sigmoid(giZ[j] + acc[1][j] + bhZ);
            float ng = fast_tanh(giN[j] + rg * (acc[2][j] + bhN));
            float h  = (1.f - zg) * ng + zg * hold[j];
            hold[j] = h;
            int row = lg * 4 + j;
            if (last) {
                out[(size_t)(bn0 + row) * Ec + w * 16 + lr] = h;
            } else {
                int bo = (row * 512 + (w * 16 + lr) * 2) ^ ((row & 7) << 4);
                *(unsigned short*)(wbuf + bo) = f2bf(h);
            }
        }
        c0 = n0; c1 = n1; c2 = n2;
        if (!last) __syncthreads();
    }
}

// ---------------------------------------------------------------------------
extern "C" void kernel_launch(void* const* d_in, const int* in_sizes, int n_in,
                              void* d_out, int out_size, void* d_ws, size_t ws_size,
                              hipStream_t stream) {
    const float* ent  = (const float*)d_in[0];
    const int*   bfeat= (const int*)  d_in[1];
    const float* Wp   = (const float*)d_in[2];
    const float* bp   = (const float*)d_in[3];
    const float* Wr   = (const float*)d_in[4];
    const float* br   = (const float*)d_in[5];
    const float* emb  = (const float*)d_in[6];
    const float* wih  = (const float*)d_in[7];
    const float* bih  = (const float*)d_in[8];
    const float* whh  = (const float*)d_in[9];
    const float* bhh  = (const float*)d_in[10];
    float* out = (float*)d_out;

    char* ws = (char*)d_ws;
    unsigned short* x    = (unsigned short*)ws;                           // 21 MB
    unsigned short* gi   = (unsigned short*)(ws + (size_t)Mrows * Ec * 2);// 63 MB
    unsigned short* wihT = (unsigned short*)(ws + (size_t)Mrows * Ec * 2
                                                + (size_t)Mrows * 768 * 2);
    unsigned short* whhT = wihT + (size_t)768 * 256;

    dim3 gx(Bc, Fc + 12);   // y>=Fc blocks do weight prep (consumed by later launches)
    k_build_x7<<<gx, 256, 0, stream>>>(ent, bfeat, Wp, bp, Wr, br, emb, x,
                                       wih, whh, wihT, whhT);

    dim3 gg(Mrows / 128, 3);
    k_gi<<<gg, 512, 0, stream>>>(x, wihT, bih, gi);

    k_gru<<<NG, 1024, 0, stream>>>(gi, whhT, bhh, out);
}